// Round 2
// baseline (4417.831 us; speedup 1.0000x reference)
//
#include <hip/hip_runtime.h>
#include <hip/hip_bf16.h>
#include <cstddef>

#define B_   2
#define S_   2048
#define H_   1024
#define NH_  16
#define D_   64
#define M_   512
#define NTOK (B_*S_)

typedef __hip_bfloat16 bf16;
__device__ __forceinline__ float toF(bf16 x) { return __bfloat162float(x); }

// ---------------------------------------------------------------------------
// dtype sniffer: reads 256 fp32-words of Wq. If the buffer actually holds
// bf16 pairs, the LOW 16 bits of each word are a bf16 ~N(0,0.02) whose
// exponent field lands in [100,126] essentially always. If it holds true
// fp32, the low 16 bits are random mantissa -> ~10% hit rate.
// flag = 1 -> buffers are bf16 ; flag = 0 -> fp32.
// ---------------------------------------------------------------------------
__global__ __launch_bounds__(256)
void detect_dtype(const unsigned int* __restrict__ w, int* __restrict__ flag)
{
    __shared__ int cnt[256];
    const int tid = threadIdx.x;
    const unsigned int x = w[tid];
    const unsigned int e0 = (x >> 7) & 0xFFu;
    cnt[tid] = (e0 >= 100u && e0 <= 126u) ? 1 : 0;
    __syncthreads();
    for (int off = 128; off > 0; off >>= 1) {
        if (tid < off) cnt[tid] += cnt[tid + off];
        __syncthreads();
    }
    if (tid == 0) flag[0] = (cnt[0] >= 128) ? 1 : 0;
}

// ---------------------------------------------------------------------------
// convert any input tensor to canonical fp32 in workspace
// ---------------------------------------------------------------------------
__global__ __launch_bounds__(256)
void convert_in(const void* __restrict__ src, float* __restrict__ dst, int n,
                const int* __restrict__ flag)
{
    const int isbf = *flag;
    for (int i = blockIdx.x * 256 + threadIdx.x; i < n; i += gridDim.x * 256)
        dst[i] = isbf ? toF(((const bf16*)src)[i]) : ((const float*)src)[i];
}

// ---------------------------------------------------------------------------
// Tiled fp32 GEMM: C[M,N] = A[M,K] @ W[K,N] (+bias); 64x64x16, 256 thr, 4x4.
// ---------------------------------------------------------------------------
__global__ __launch_bounds__(256)
void gemm_tn(const float* __restrict__ A, const float* __restrict__ W,
             const float* __restrict__ bias, float* __restrict__ C,
             int M, int N, int K, int accumulate)
{
    __shared__ float As[16][68];
    __shared__ float Bs[16][68];
    const int tid = threadIdx.x;
    const int tx = tid & 15, ty = tid >> 4;
    const int m0 = blockIdx.y * 64, n0 = blockIdx.x * 64;
    float acc[4][4] = {};

    for (int k0 = 0; k0 < K; k0 += 16) {
        {
            const int r  = tid >> 2;
            const int cg = (tid & 3) * 4;
            const float* ap = A + (size_t)(m0 + r) * K + (k0 + cg);
            #pragma unroll
            for (int j = 0; j < 4; ++j) As[cg + j][r] = ap[j];
        }
        {
            const int r  = tid >> 4;
            const int cg = (tid & 15) * 4;
            const float* wp = W + (size_t)(k0 + r) * N + (n0 + cg);
            #pragma unroll
            for (int j = 0; j < 4; ++j) Bs[r][cg + j] = wp[j];
        }
        __syncthreads();
        #pragma unroll
        for (int kk = 0; kk < 16; ++kk) {
            float a[4], b[4];
            #pragma unroll
            for (int i = 0; i < 4; ++i) a[i] = As[kk][ty * 4 + i];
            #pragma unroll
            for (int j = 0; j < 4; ++j) b[j] = Bs[kk][tx * 4 + j];
            #pragma unroll
            for (int i = 0; i < 4; ++i)
                #pragma unroll
                for (int j = 0; j < 4; ++j)
                    acc[i][j] += a[i] * b[j];
        }
        __syncthreads();
    }

    #pragma unroll
    for (int i = 0; i < 4; ++i) {
        const int row = m0 + ty * 4 + i;
        #pragma unroll
        for (int j = 0; j < 4; ++j) {
            const int col = n0 + tx * 4 + j;
            float v = acc[i][j];
            if (bias) v += bias[col];
            const size_t idx = (size_t)row * N + col;
            if (accumulate) C[idx] += v; else C[idx] = v;
        }
    }
}

// ---------------------------------------------------------------------------
// med logits: out[b,s,t] = sum_m mq[b,s,m]*mk[b,t,m]
// ---------------------------------------------------------------------------
__global__ __launch_bounds__(256)
void med_logits(const float* __restrict__ mq, const float* __restrict__ mk,
                float* __restrict__ out)
{
    const int b = blockIdx.z;
    const float* A  = mq + (size_t)b * S_ * M_;
    const float* Bm = mk + (size_t)b * S_ * M_;
    __shared__ float As[16][68];
    __shared__ float Bs[16][68];
    const int tid = threadIdx.x;
    const int tx = tid & 15, ty = tid >> 4;
    const int m0 = blockIdx.y * 64, n0 = blockIdx.x * 64;
    float acc[4][4] = {};

    for (int k0 = 0; k0 < M_; k0 += 16) {
        const int r  = tid >> 2;
        const int cg = (tid & 3) * 4;
        const float* ap = A  + (size_t)(m0 + r) * M_ + (k0 + cg);
        const float* bp = Bm + (size_t)(n0 + r) * M_ + (k0 + cg);
        #pragma unroll
        for (int j = 0; j < 4; ++j) { As[cg + j][r] = ap[j]; Bs[cg + j][r] = bp[j]; }
        __syncthreads();
        #pragma unroll
        for (int kk = 0; kk < 16; ++kk) {
            float a[4], b[4];
            #pragma unroll
            for (int i = 0; i < 4; ++i) a[i] = As[kk][ty * 4 + i];
            #pragma unroll
            for (int j = 0; j < 4; ++j) b[j] = Bs[kk][tx * 4 + j];
            #pragma unroll
            for (int i = 0; i < 4; ++i)
                #pragma unroll
                for (int j = 0; j < 4; ++j)
                    acc[i][j] += a[i] * b[j];
        }
        __syncthreads();
    }
    #pragma unroll
    for (int i = 0; i < 4; ++i)
        #pragma unroll
        for (int j = 0; j < 4; ++j)
            out[(size_t)b * S_ * S_ + (size_t)(m0 + ty * 4 + i) * S_ + (n0 + tx * 4 + j)]
                = acc[i][j];
}

// ---------------------------------------------------------------------------
// in-place row softmax (fp32), one block per row of S_ columns
// ---------------------------------------------------------------------------
__global__ __launch_bounds__(256)
void row_softmax(float* __restrict__ x)
{
    float* p = x + (size_t)blockIdx.x * S_;
    __shared__ float red[256];
    const int tid = threadIdx.x;

    float m = -1e30f;
    for (int i = tid; i < S_; i += 256) m = fmaxf(m, p[i]);
    red[tid] = m; __syncthreads();
    for (int off = 128; off > 0; off >>= 1) {
        if (tid < off) red[tid] = fmaxf(red[tid], red[tid + off]);
        __syncthreads();
    }
    const float mx = red[0];
    __syncthreads();

    float s = 0.f;
    for (int i = tid; i < S_; i += 256) {
        float e = __expf(fmaxf(p[i] - mx, -80.f));
        p[i] = e; s += e;
    }
    red[tid] = s; __syncthreads();
    for (int off = 128; off > 0; off >>= 1) {
        if (tid < off) red[tid] += red[tid + off];
        __syncthreads();
    }
    const float inv = 1.f / fmaxf(red[0], 1e-30f);
    for (int i = tid; i < S_; i += 256) p[i] *= inv;
}

// ---------------------------------------------------------------------------
// scores + softmax + probs write (dtype-dispatched). 4 s-rows per block.
// ---------------------------------------------------------------------------
__global__ __launch_bounds__(256)
void scores_softmax(const float* __restrict__ q, const float* __restrict__ k,
                    const float* __restrict__ medp, void* __restrict__ dout,
                    const int* __restrict__ flag)
{
    const int isbf = *flag;
    const int bh = blockIdx.y;
    const int b = bh >> 4, h = bh & 15;
    const int s0 = blockIdx.x * 4;
    __shared__ float qs[4][64];
    __shared__ float sc[4][2048];
    __shared__ float red[256];
    const int tid = threadIdx.x;

    {
        const int r = tid >> 6, d = tid & 63;
        qs[r][d] = q[(size_t)(b * S_ + s0 + r) * H_ + h * D_ + d];
    }
    __syncthreads();

    const float* kb = k + (size_t)b * S_ * H_ + h * D_;
    const float* mb = medp + ((size_t)b * S_ + s0) * S_;

    for (int rb = 0; rb < 8; ++rb) {
        const int t = tid + rb * 256;
        const float4* k4 = (const float4*)(kb + (size_t)t * H_);
        float a0 = 0.f, a1 = 0.f, a2 = 0.f, a3 = 0.f;
        #pragma unroll
        for (int i = 0; i < 16; ++i) {
            const float4 kv = k4[i];
            const int d = i * 4;
            a0 += qs[0][d]*kv.x + qs[0][d+1]*kv.y + qs[0][d+2]*kv.z + qs[0][d+3]*kv.w;
            a1 += qs[1][d]*kv.x + qs[1][d+1]*kv.y + qs[1][d+2]*kv.z + qs[1][d+3]*kv.w;
            a2 += qs[2][d]*kv.x + qs[2][d+1]*kv.y + qs[2][d+2]*kv.z + qs[2][d+3]*kv.w;
            a3 += qs[3][d]*kv.x + qs[3][d+1]*kv.y + qs[3][d+2]*kv.z + qs[3][d+3]*kv.w;
        }
        sc[0][t] = a0 * 0.125f + 0.3f * mb[t];
        sc[1][t] = a1 * 0.125f + 0.3f * mb[(size_t)S_ + t];
        sc[2][t] = a2 * 0.125f + 0.3f * mb[(size_t)2 * S_ + t];
        sc[3][t] = a3 * 0.125f + 0.3f * mb[(size_t)3 * S_ + t];
    }
    __syncthreads();

    const size_t pbase = (size_t)NTOK * H_ + ((size_t)(b * NH_ + h) * S_ + s0) * S_;
    bf16*  pb_b = (bf16*)dout  + pbase;
    float* pb_f = (float*)dout + pbase;

    for (int r = 0; r < 4; ++r) {
        float m = -1e30f;
        for (int i = tid; i < S_; i += 256) m = fmaxf(m, sc[r][i]);
        red[tid] = m; __syncthreads();
        for (int off = 128; off > 0; off >>= 1) {
            if (tid < off) red[tid] = fmaxf(red[tid], red[tid + off]);
            __syncthreads();
        }
        const float mx = red[0];
        __syncthreads();

        float s = 0.f;
        for (int i = tid; i < S_; i += 256) {
            float e = __expf(fmaxf(sc[r][i] - mx, -80.f));
            sc[r][i] = e; s += e;
        }
        red[tid] = s; __syncthreads();
        for (int off = 128; off > 0; off >>= 1) {
            if (tid < off) red[tid] += red[tid + off];
            __syncthreads();
        }
        const float inv = 1.f / fmaxf(red[0], 1e-30f);
        __syncthreads();
        for (int i = tid; i < S_; i += 256) {
            const float pv = sc[r][i] * inv;
            if (isbf) pb_b[(size_t)r * S_ + i] = __float2bfloat16(pv);
            else      pb_f[(size_t)r * S_ + i] = pv;
        }
    }
}

// ---------------------------------------------------------------------------
// ctx = probs @ v  (probs read back from d_out, dtype-dispatched)
// ---------------------------------------------------------------------------
__global__ __launch_bounds__(256)
void pv_gemm(const void* __restrict__ dout, const float* __restrict__ v,
             float* __restrict__ ctx, const int* __restrict__ flag)
{
    const int isbf = *flag;
    const int bh = blockIdx.y;
    const int b = bh >> 4, h = bh & 15;
    const int m0 = blockIdx.x * 64;
    const size_t pbase = (size_t)NTOK * H_ + (size_t)bh * S_ * S_;
    const bf16*  Ab = (const bf16*)dout  + pbase;
    const float* Af = (const float*)dout + pbase;
    const float* Bv = v + (size_t)b * S_ * H_ + h * D_;
    __shared__ float As[16][68];
    __shared__ float Bs[16][68];
    const int tid = threadIdx.x;
    const int tx = tid & 15, ty = tid >> 4;
    float acc[4][4] = {};

    for (int k0 = 0; k0 < S_; k0 += 16) {
        {
            const int r  = tid >> 2;
            const int cg = (tid & 3) * 4;
            const size_t base = (size_t)(m0 + r) * S_ + (k0 + cg);
            #pragma unroll
            for (int j = 0; j < 4; ++j)
                As[cg + j][r] = isbf ? toF(Ab[base + j]) : Af[base + j];
        }
        {
            const int r  = tid >> 4;
            const int cg = (tid & 15) * 4;
            const float* bp = Bv + (size_t)(k0 + r) * H_ + cg;
            #pragma unroll
            for (int j = 0; j < 4; ++j) Bs[r][cg + j] = bp[j];
        }
        __syncthreads();
        #pragma unroll
        for (int kk = 0; kk < 16; ++kk) {
            float a[4], bb[4];
            #pragma unroll
            for (int i = 0; i < 4; ++i) a[i]  = As[kk][ty * 4 + i];
            #pragma unroll
            for (int j = 0; j < 4; ++j) bb[j] = Bs[kk][tx * 4 + j];
            #pragma unroll
            for (int i = 0; i < 4; ++i)
                #pragma unroll
                for (int j = 0; j < 4; ++j)
                    acc[i][j] += a[i] * bb[j];
        }
        __syncthreads();
    }
    #pragma unroll
    for (int i = 0; i < 4; ++i)
        #pragma unroll
        for (int j = 0; j < 4; ++j)
            ctx[(size_t)(b * S_ + m0 + ty * 4 + i) * H_ + h * D_ + tx * 4 + j] = acc[i][j];
}

// ---------------------------------------------------------------------------
// out0 = LayerNorm(f + hs) * g + beta   (dtype-dispatched write)
// ---------------------------------------------------------------------------
__global__ __launch_bounds__(256)
void add_ln(const float* __restrict__ f, const float* __restrict__ hs,
            const float* __restrict__ g, const float* __restrict__ bta,
            void* __restrict__ dout, const int* __restrict__ flag)
{
    const int isbf = *flag;
    const int row = blockIdx.x;
    const int tid = threadIdx.x;
    __shared__ float red[256];
    float x[4];
    #pragma unroll
    for (int i = 0; i < 4; ++i) {
        const int c = tid + i * 256;
        x[i] = f[(size_t)row * H_ + c] + hs[(size_t)row * H_ + c];
    }
    float s = x[0] + x[1] + x[2] + x[3];
    red[tid] = s; __syncthreads();
    for (int off = 128; off > 0; off >>= 1) {
        if (tid < off) red[tid] += red[tid + off];
        __syncthreads();
    }
    const float mu = red[0] * (1.f / (float)H_);
    __syncthreads();

    float vs = 0.f;
    #pragma unroll
    for (int i = 0; i < 4; ++i) { const float d = x[i] - mu; vs += d * d; }
    red[tid] = vs; __syncthreads();
    for (int off = 128; off > 0; off >>= 1) {
        if (tid < off) red[tid] += red[tid + off];
        __syncthreads();
    }
    const float var = red[0] * (1.f / (float)H_);
    const float inv = 1.f / sqrtf(var + 1e-12f);
    bf16*  ob = (bf16*)dout;
    float* of = (float*)dout;
    #pragma unroll
    for (int i = 0; i < 4; ++i) {
        const int c = tid + i * 256;
        const float y = (x[i] - mu) * inv * g[c] + bta[c];
        if (isbf) ob[(size_t)row * H_ + c] = __float2bfloat16(y);
        else      of[(size_t)row * H_ + c] = y;
    }
}

// ---------------------------------------------------------------------------
extern "C" void kernel_launch(void* const* d_in, const int* in_sizes, int n_in,
                              void* d_out, int out_size, void* d_ws, size_t ws_size,
                              hipStream_t stream)
{
    // header: dtype flag
    int* flag = (int*)d_ws;
    float* p = (float*)((char*)d_ws + 256);

    // converted-input fp32 buffers
    float* hs_f  = p; p += (size_t)NTOK * H_;
    float* mc_f  = p; p += (size_t)NTOK * H_;
    float* Wq_f  = p; p += (size_t)H_ * H_;
    float* Wk_f  = p; p += (size_t)H_ * H_;
    float* Wv_f  = p; p += (size_t)H_ * H_;
    float* Wmq_f = p; p += (size_t)H_ * M_;
    float* Wmk_f = p; p += (size_t)H_ * M_;
    float* Wc_f  = p; p += (size_t)H_ * M_;
    float* Wf_f  = p; p += (size_t)(H_ + M_) * H_;
    float* bq_f  = p; p += H_;
    float* bk_f  = p; p += H_;
    float* bv_f  = p; p += H_;
    float* bmq_f = p; p += M_;
    float* bmk_f = p; p += M_;
    float* bc_f  = p; p += M_;
    float* bf_f  = p; p += H_;
    float* lng_f = p; p += H_;
    float* lnb_f = p; p += H_;

    // pipeline fp32 buffers
    float* q    = p; p += (size_t)NTOK * H_;
    float* k    = p; p += (size_t)NTOK * H_;
    float* v    = p; p += (size_t)NTOK * H_;
    float* mq   = p; p += (size_t)NTOK * M_;
    float* mk   = p; p += (size_t)NTOK * M_;
    float* medp = p; p += (size_t)B_ * S_ * S_;
    float* ctx  = p; p += (size_t)NTOK * H_;
    float* clin = p; p += (size_t)NTOK * M_;
    float* fbuf = p; p += (size_t)NTOK * H_;

    const dim3 blk(256);

    // 1) dtype detection from Wq
    detect_dtype<<<1, blk, 0, stream>>>((const unsigned int*)d_in[2], flag);

    // 2) convert all inputs to fp32
    float* dsts[18] = { hs_f, mc_f, Wq_f, bq_f, Wk_f, bk_f, Wv_f, bv_f,
                        Wmq_f, bmq_f, Wmk_f, bmk_f, Wc_f, bc_f, Wf_f, bf_f,
                        lng_f, lnb_f };
    for (int i = 0; i < 18; ++i) {
        const int n = in_sizes[i];
        const int g = (n + 255) / 256;
        convert_in<<<dim3(g > 1024 ? 1024 : g), blk, 0, stream>>>(d_in[i], dsts[i], n, flag);
    }

    // 3) projections (fp32 tiled GEMMs)
    gemm_tn<<<dim3(16, 64), blk, 0, stream>>>(hs_f, Wq_f, bq_f, q, NTOK, H_, H_, 0);
    gemm_tn<<<dim3(16, 64), blk, 0, stream>>>(hs_f, Wk_f, bk_f, k, NTOK, H_, H_, 0);
    gemm_tn<<<dim3(16, 64), blk, 0, stream>>>(hs_f, Wv_f, bv_f, v, NTOK, H_, H_, 0);
    gemm_tn<<<dim3(8, 64),  blk, 0, stream>>>(hs_f, Wmq_f, bmq_f, mq, NTOK, M_, H_, 0);
    gemm_tn<<<dim3(8, 64),  blk, 0, stream>>>(mc_f, Wmk_f, bmk_f, mk, NTOK, M_, H_, 0);

    // 4) medical bias path
    med_logits<<<dim3(32, 32, 2), blk, 0, stream>>>(mq, mk, medp);
    row_softmax<<<dim3(B_ * S_), blk, 0, stream>>>(medp);

    // 5) attention scores + softmax -> probs (output 1)
    scores_softmax<<<dim3(S_ / 4, 32), blk, 0, stream>>>(q, k, medp, d_out, flag);

    // 6) ctx = probs @ v
    pv_gemm<<<dim3(32, 32), blk, 0, stream>>>(d_out, v, ctx, flag);

    // 7) clin = ctx@Wc + bc ; fbuf = ctx@Wf_top + clin@Wf_bot + bf
    gemm_tn<<<dim3(8, 64),  blk, 0, stream>>>(ctx, Wc_f, bc_f, clin, NTOK, M_, H_, 0);
    gemm_tn<<<dim3(16, 64), blk, 0, stream>>>(ctx, Wf_f, bf_f, fbuf, NTOK, H_, H_, 0);
    gemm_tn<<<dim3(16, 64), blk, 0, stream>>>(clin, Wf_f + (size_t)H_ * H_, (const float*)nullptr,
                                              fbuf, NTOK, H_, M_, 1);

    // 8) residual + layernorm -> output 0
    add_ln<<<dim3(NTOK), blk, 0, stream>>>(fbuf, hs_f, lng_f, lnb_f, d_out, flag);
}